// Round 6
// baseline (571.498 us; speedup 1.0000x reference)
//
#include <hip/hip_runtime.h>
#include <hip/hip_cooperative_groups.h>

namespace cg = cooperative_groups;

typedef unsigned short ushort_t;
typedef __attribute__((ext_vector_type(8))) short short8;
typedef __attribute__((ext_vector_type(8))) unsigned short us8v;
typedef __attribute__((ext_vector_type(4))) float f32x4;

__device__ __forceinline__ float b2f(unsigned short u) {
    union { unsigned int i; float f; } v; v.i = ((unsigned int)u) << 16; return v.f;
}
__device__ __forceinline__ unsigned short f2b(float f) {
    union { float f; unsigned int i; } v; v.f = f;
    unsigned int r = (v.i + 0x7FFF + ((v.i >> 16) & 1)) >> 16;
    return (unsigned short)r;
}

// int64 path: low words carry the value (nonneg < 2^31); 8B coalesced loads
__device__ __forceinline__ void load_edge(const int* __restrict__ ei, int e, int E,
                                          int is64, int& s, int& d) {
    if (is64) {
        const long long* el = (const long long*)ei;
        s = (int)el[e]; d = (int)el[E + e];
    } else {
        s = ei[e]; d = ei[E + e];
    }
}

// detection: odd int32 words of first 512 entries all zero => int64
__device__ __forceinline__ int detect64(const int* __restrict__ ei, int t) {
    int z = 0;
    for (int i = t; i < 512; i += 256) z |= ei[2 * i + 1];
    return (__syncthreads_or(z) == 0);
}

// ======================= fused CSR build (cooperative) ====================
// Phases (identical memory patterns to the proven 6-kernel pipeline):
//  1 hist -> 2 scan -> 3 bucket scatter -> 4 per-bucket count ->
//  5 padded scan/assign -> 6 per-bucket fill -> 7 W transpose + zero row
__global__ __launch_bounds__(256) void k_csr(
        const int* __restrict__ ei, int E, unsigned N, int Ni, int NB, int BSH,
        int nch, int gN,
        int* __restrict__ bhist, int* __restrict__ bkbase, int* __restrict__ bkcur,
        int* __restrict__ cnt, int* __restrict__ pos, float* __restrict__ dinv,
        int* __restrict__ cursor, int* __restrict__ srcs,
        int* __restrict__ bs, int* __restrict__ bd,
        const float* __restrict__ W1, const float* __restrict__ W2,
        ushort_t* __restrict__ WT, ushort_t* __restrict__ xt) {
    cg::grid_group grid = cg::this_grid();
    __shared__ int smem[8704];             // 34 KB, aliased per phase
    int* lss = smem;                       // [4096]
    int* ldd = smem + 4096;                // [4096]
    int* lhist = smem + 8192;              // [256]
    int* lcur = smem + 8448;               // [256]
    int t = threadIdx.x;
    int b = blockIdx.x;

    // ---- phase 1: bucket histogram ----
    if (b < nch) {
        for (int q = t; q < NB; q += 256) lhist[q] = 0;
        int is64 = detect64(ei, t);        // includes __syncthreads
        int e0 = b * 4096;
        #pragma unroll
        for (int i = 0; i < 16; ++i) {
            int e = e0 + i * 256 + t;
            if (e < E) {
                int s, d; load_edge(ei, e, E, is64, s, d);
                if ((unsigned)s < N && (unsigned)d < N) atomicAdd(&lhist[d >> BSH], 1);
            }
        }
        __syncthreads();
        for (int q = t; q < NB; q += 256) {
            int v = lhist[q]; if (v) atomicAdd(&bhist[q], v);
        }
    }
    grid.sync();

    // ---- phase 2: exclusive scan of bucket hist (block 0) ----
    if (b == 0) {
        int v0 = (t < NB) ? bhist[t] : 0;
        smem[t] = v0;
        for (int o = 1; o < 256; o <<= 1) {
            __syncthreads();
            int v = (t >= o) ? smem[t - o] : 0;
            __syncthreads();
            smem[t] += v;
        }
        __syncthreads();
        if (t < NB) { int ex = smem[t] - v0; bkbase[t] = ex; bkcur[t] = ex; }
    }
    grid.sync();

    // ---- phase 3: bucket scatter ----
    if (b < nch) {
        for (int q = t; q < NB; q += 256) lhist[q] = 0;
        int is64 = detect64(ei, t);
        int e0 = b * 4096;
        #pragma unroll
        for (int i = 0; i < 16; ++i) {
            int idx = i * 256 + t, e = e0 + idx;
            int s = -1, d = -1;
            if (e < E) {
                load_edge(ei, e, E, is64, s, d);
                if (!((unsigned)s < N && (unsigned)d < N)) d = -1;
            }
            lss[idx] = s; ldd[idx] = d;
            if (d >= 0) atomicAdd(&lhist[d >> BSH], 1);
        }
        __syncthreads();
        for (int q = t; q < NB; q += 256) {
            int v = lhist[q];
            lcur[q] = v ? atomicAdd(&bkcur[q], v) : 0;
        }
        __syncthreads();
        #pragma unroll
        for (int i = 0; i < 16; ++i) {
            int idx = i * 256 + t;
            int d = ldd[idx];
            if (d >= 0) {
                int p = atomicAdd(&lcur[d >> BSH], 1);
                bs[p] = lss[idx]; bd[p] = d;
            }
        }
    }
    grid.sync();

    // ---- phase 4: per-bucket degree count (LDS counters) ----
    if (b < NB) {
        int nbase = b << BSH;
        int nn = min(1 << BSH, Ni - nbase);
        for (int q = t; q < nn; q += 256) smem[q] = 0;
        __syncthreads();
        int s0 = bkbase[b], s1 = bkcur[b];
        for (int i = s0 + t; i < s1; i += 256) atomicAdd(&smem[bd[i] - nbase], 1);
        __syncthreads();
        for (int q = t; q < nn; q += 256) cnt[nbase + q] = smem[q];
    }
    grid.sync();

    // ---- phase 5: padded scan -> pos; dinv; pad srcs ----
    if (b < gN) {
        int n = b * 256 + t;
        int c = (n < Ni) ? cnt[n] : 0;
        int cp = (c + 7) & ~7;             // pad each list to multiple of 8
        smem[t] = cp;
        for (int o = 1; o < 256; o <<= 1) {
            __syncthreads();
            int v = (t >= o) ? smem[t - o] : 0;
            __syncthreads();
            smem[t] += v;
        }
        __syncthreads();
        if (t == 255) smem[256] = atomicAdd(cursor, smem[255]);
        __syncthreads();
        int sbase = smem[256];
        if (n < Ni) {
            int st = sbase + smem[t] - cp;  // exclusive start (never mutated)
            pos[n] = st;
            dinv[n] = rsqrtf((float)c + 1.0f);
            cnt[n] = cp;
            for (int q = c; q < cp; ++q) srcs[st + q] = Ni;  // pads -> zero row
        }
    }
    grid.sync();

    // ---- phase 6: per-bucket CSR fill (LDS cursors) ----
    if (b < NB) {
        int nbase = b << BSH;
        int nn = min(1 << BSH, Ni - nbase);
        for (int q = t; q < nn; q += 256) smem[q] = pos[nbase + q];
        __syncthreads();
        int s0 = bkbase[b], s1 = bkcur[b];
        for (int i = s0 + t; i < s1; i += 256) {
            int d = bd[i];
            int p = atomicAdd(&smem[d - nbase], 1);
            srcs[p] = bs[i];
        }
    }

    // ---- phase 7: W transpose + zero row (no sync needed after) ----
    if (b == nch) {
        for (int i = t; i < 16384; i += 256) {
            int n = i >> 7, k = i & 127;
            WT[i] = f2b(W1[k * 128 + n]);
        }
    } else if (b == nch + 1) {
        for (int i = t; i < 16384; i += 256) {
            int n = i >> 7, k = i & 127;
            WT[16384 + i] = f2b(W2[k * 128 + n]);
        }
    } else if (b == nch + 2) {
        if (t < 128) xt[((size_t)Ni << 7) + t] = 0;   // zero row for pad gathers
    }
}

// ============== fallback path: the proven separate kernels ===============
__global__ void k_hist(const int* __restrict__ ei, int E, unsigned N,
                       int* __restrict__ bhist, int BSH, int NB) {
    __shared__ int lh[256];
    int t = threadIdx.x;
    for (int b = t; b < NB; b += 256) lh[b] = 0;
    int is64 = detect64(ei, t);
    int e0 = blockIdx.x * 4096;
    #pragma unroll
    for (int i = 0; i < 16; ++i) {
        int e = e0 + i * 256 + t;
        if (e < E) {
            int s, d; load_edge(ei, e, E, is64, s, d);
            if ((unsigned)s < N && (unsigned)d < N) atomicAdd(&lh[d >> BSH], 1);
        }
    }
    __syncthreads();
    for (int b = t; b < NB; b += 256) { int v = lh[b]; if (v) atomicAdd(&bhist[b], v); }
}

__global__ void k_scanb(const int* __restrict__ bhist, int NB,
                        int* __restrict__ bkbase, int* __restrict__ bkcur) {
    __shared__ int sd[256];
    int t = threadIdx.x;
    int v0 = (t < NB) ? bhist[t] : 0;
    sd[t] = v0;
    for (int o = 1; o < 256; o <<= 1) {
        __syncthreads();
        int v = (t >= o) ? sd[t - o] : 0;
        __syncthreads();
        sd[t] += v;
    }
    __syncthreads();
    if (t < NB) { int ex = sd[t] - v0; bkbase[t] = ex; bkcur[t] = ex; }
}

__global__ __launch_bounds__(256) void k_bucket(const int* __restrict__ ei, int E, unsigned N,
                                                int* __restrict__ bkcur,
                                                int* __restrict__ bs, int* __restrict__ bd,
                                                int BSH, int NB) {
    __shared__ int lss[4096];
    __shared__ int ldd[4096];
    __shared__ int lhist[256];
    __shared__ int lcur[256];
    int t = threadIdx.x;
    int e0 = blockIdx.x * 4096;
    for (int b = t; b < NB; b += 256) lhist[b] = 0;
    int is64 = detect64(ei, t);
    #pragma unroll
    for (int i = 0; i < 16; ++i) {
        int idx = i * 256 + t, e = e0 + idx;
        int s = -1, d = -1;
        if (e < E) {
            load_edge(ei, e, E, is64, s, d);
            if (!((unsigned)s < N && (unsigned)d < N)) d = -1;
        }
        lss[idx] = s; ldd[idx] = d;
        if (d >= 0) atomicAdd(&lhist[d >> BSH], 1);
    }
    __syncthreads();
    for (int b = t; b < NB; b += 256) {
        int v = lhist[b];
        lcur[b] = v ? atomicAdd(&bkcur[b], v) : 0;
    }
    __syncthreads();
    #pragma unroll
    for (int i = 0; i < 16; ++i) {
        int idx = i * 256 + t;
        int d = ldd[idx];
        if (d >= 0) {
            int p = atomicAdd(&lcur[d >> BSH], 1);
            bs[p] = lss[idx]; bd[p] = d;
        }
    }
}

__global__ void k_count2(const int* __restrict__ bd, const int* __restrict__ bkbase,
                         const int* __restrict__ bkcur, int N, int BSH,
                         int* __restrict__ cnt) {
    __shared__ int lc[512];
    int b = blockIdx.x, t = threadIdx.x;
    int nbase = b << BSH;
    int nn = min(1 << BSH, N - nbase);
    for (int j = t; j < nn; j += 256) lc[j] = 0;
    __syncthreads();
    int s0 = bkbase[b], s1 = bkcur[b];
    for (int i = s0 + t; i < s1; i += 256) atomicAdd(&lc[bd[i] - nbase], 1);
    __syncthreads();
    for (int j = t; j < nn; j += 256) cnt[nbase + j] = lc[j];
}

__global__ void k_assign(int* __restrict__ cnt, int N,
                         int* __restrict__ pos, float* __restrict__ dinv,
                         int* __restrict__ cursor, int* __restrict__ srcs,
                         int padidx) {
    __shared__ int sd[256];
    __shared__ int sbase;
    int t = threadIdx.x;
    int n = blockIdx.x * 256 + t;
    int c = (n < N) ? cnt[n] : 0;
    int cp = (c + 7) & ~7;
    sd[t] = cp;
    for (int o = 1; o < 256; o <<= 1) {
        __syncthreads();
        int v = (t >= o) ? sd[t - o] : 0;
        __syncthreads();
        sd[t] += v;
    }
    __syncthreads();
    if (t == 255) sbase = atomicAdd(cursor, sd[255]);
    __syncthreads();
    if (n < N) {
        int st = sbase + sd[t] - cp;
        pos[n] = st;
        dinv[n] = rsqrtf((float)c + 1.0f);
        cnt[n] = cp;
        for (int q = c; q < cp; ++q) srcs[st + q] = padidx;
    }
}

__global__ void k_fill2(const int* __restrict__ bs, const int* __restrict__ bd,
                        const int* __restrict__ bkbase, const int* __restrict__ bkcur,
                        const int* __restrict__ pos, int N, int BSH,
                        int* __restrict__ srcs) {
    __shared__ int lcur[512];
    int b = blockIdx.x, t = threadIdx.x;
    int nbase = b << BSH;
    int nn = min(1 << BSH, N - nbase);
    for (int j = t; j < nn; j += 256) lcur[j] = pos[nbase + j];
    __syncthreads();
    int s0 = bkbase[b], s1 = bkcur[b];
    for (int i = s0 + t; i < s1; i += 256) {
        int d = bd[i];
        int p = atomicAdd(&lcur[d - nbase], 1);
        srcs[p] = bs[i];
    }
}

__global__ void k_transpose(const float* __restrict__ W1, const float* __restrict__ W2,
                            ushort_t* __restrict__ WT, ushort_t* __restrict__ xt,
                            int N) {
    if (blockIdx.x == 2) {
        int t = threadIdx.x;
        if (t < 128) xt[((size_t)N << 7) + t] = 0;
        return;
    }
    const float* src = blockIdx.x ? W2 : W1;
    ushort_t* dst = WT + blockIdx.x * 16384;
    for (int i = threadIdx.x; i < 16384; i += 256) {
        int n = i >> 7, k = i & 127;
        dst[i] = f2b(src[k * 128 + n]);
    }
}

// ---- GEMM: C[M,128] = dinv[m] * (A[M,128] @ W[128,128]); C bf16 ---------
template <bool ABF>
__global__ __launch_bounds__(256) void k_gemm(const void* __restrict__ Ap,
                                              const ushort_t* __restrict__ WT,
                                              ushort_t* __restrict__ C,
                                              const float* __restrict__ dinv, int M) {
    __shared__ __align__(16) ushort_t sA[64 * 136];
    __shared__ __align__(16) ushort_t sW[128 * 136];
    int t = threadIdx.x;
    int row0 = blockIdx.x * 64;

    #pragma unroll
    for (int it = 0; it < 8; ++it) {
        int flat = (it * 256 + t) * 8;
        int n = flat >> 7, k = flat & 127;
        uint4 v = *(const uint4*)(WT + flat);
        *(uint4*)(&sW[n * 136 + k]) = v;
    }
    #pragma unroll
    for (int it = 0; it < 4; ++it) {
        int flat = (it * 256 + t) * 8;
        int r = flat >> 7, cc = flat & 127;
        int row = row0 + r; if (row > M - 1) row = M - 1;
        if (ABF) {
            const ushort_t* A = (const ushort_t*)Ap;
            us8v v = *(const us8v*)(A + ((size_t)row << 7) + cc);
            *(us8v*)(&sA[r * 136 + cc]) = v;
        } else {
            const float* A = (const float*)Ap;
            const float* p = A + (size_t)row * 128 + cc;
            float4 f0 = *(const float4*)p;
            float4 f1 = *(const float4*)(p + 4);
            ushort_t tmp[8] __attribute__((aligned(16)));
            tmp[0] = f2b(f0.x); tmp[1] = f2b(f0.y); tmp[2] = f2b(f0.z); tmp[3] = f2b(f0.w);
            tmp[4] = f2b(f1.x); tmp[5] = f2b(f1.y); tmp[6] = f2b(f1.z); tmp[7] = f2b(f1.w);
            *(uint4*)(&sA[r * 136 + cc]) = *(const uint4*)tmp;
        }
    }
    __syncthreads();

    int w = t >> 6, lane = t & 63;
    int m = lane & 15, quad = lane >> 4;

    f32x4 acc[8] = {};
    #pragma unroll
    for (int k0 = 0; k0 < 128; k0 += 32) {
        short8 af = *(const short8*)(&sA[(w * 16 + m) * 136 + k0 + quad * 8]);
        #pragma unroll
        for (int tt = 0; tt < 8; ++tt) {
            short8 bf = *(const short8*)(&sW[(tt * 16 + m) * 136 + k0 + quad * 8]);
            acc[tt] = __builtin_amdgcn_mfma_f32_16x16x32_bf16(af, bf, acc[tt], 0, 0, 0);
        }
    }
    #pragma unroll
    for (int r = 0; r < 4; ++r) {
        int row = row0 + w * 16 + quad * 4 + r;
        if (row < M) {
            float dd = dinv[row];
            #pragma unroll
            for (int tt = 0; tt < 8; ++tt)
                C[(size_t)row * 128 + tt * 16 + m] = f2b(dd * acc[tt][r]);
        }
    }
}

// ---- Aggregation over pre-scaled xt: out[d] = dinv[d]*(sum + xt[d]) + b -
template <bool OBF>
__global__ __launch_bounds__(256) void k_agg(const ushort_t* __restrict__ xt,
                                             const float* __restrict__ bias,
                                             void* __restrict__ outp,
                                             const int* __restrict__ pos,
                                             const int* __restrict__ cnts,
                                             const float* __restrict__ dinv,
                                             const int* __restrict__ srcs, int N) {
    int lane = threadIdx.x & 63;
    int slot = lane >> 4, j = lane & 15;
    int d = (blockIdx.x << 2) + (threadIdx.x >> 6);
    if (d >= N) return;
    int cn = cnts[d];                       // padded (multiple of 8)
    int start = pos[d];
    float dd = dinv[d];
    us8v vs = *(const us8v*)(xt + ((size_t)d << 7) + (j << 3));
    float4 bb0 = *(const float4*)(bias + (j << 3));
    float4 bb1 = *(const float4*)(bias + (j << 3) + 4);

    float a0 = 0.f, a1 = 0.f, a2 = 0.f, a3 = 0.f;
    float a4 = 0.f, a5 = 0.f, a6 = 0.f, a7 = 0.f;

    for (int base = 0; base < cn; base += 64) {
        int n = cn - base; if (n > 64) n = 64;   // multiple of 8, >= 8
        int sv = 0;
        if (lane < n) sv = srcs[start + base + lane];
        int s0 = __shfl(sv, slot);
        int s1 = __shfl(sv, 4 + slot);
        us8v v0 = *(const us8v*)(xt + ((size_t)s0 << 7) + (j << 3));
        us8v v1 = *(const us8v*)(xt + ((size_t)s1 << 7) + (j << 3));
        for (int c = 8; c < n; c += 8) {
            int t0 = __shfl(sv, c + slot);
            int t1 = __shfl(sv, c + 4 + slot);
            us8v w0 = *(const us8v*)(xt + ((size_t)t0 << 7) + (j << 3));
            us8v w1 = *(const us8v*)(xt + ((size_t)t1 << 7) + (j << 3));
            a0 += b2f(v0[0]); a1 += b2f(v0[1]); a2 += b2f(v0[2]); a3 += b2f(v0[3]);
            a4 += b2f(v0[4]); a5 += b2f(v0[5]); a6 += b2f(v0[6]); a7 += b2f(v0[7]);
            a0 += b2f(v1[0]); a1 += b2f(v1[1]); a2 += b2f(v1[2]); a3 += b2f(v1[3]);
            a4 += b2f(v1[4]); a5 += b2f(v1[5]); a6 += b2f(v1[6]); a7 += b2f(v1[7]);
            v0 = w0; v1 = w1;
        }
        a0 += b2f(v0[0]); a1 += b2f(v0[1]); a2 += b2f(v0[2]); a3 += b2f(v0[3]);
        a4 += b2f(v0[4]); a5 += b2f(v0[5]); a6 += b2f(v0[6]); a7 += b2f(v0[7]);
        a0 += b2f(v1[0]); a1 += b2f(v1[1]); a2 += b2f(v1[2]); a3 += b2f(v1[3]);
        a4 += b2f(v1[4]); a5 += b2f(v1[5]); a6 += b2f(v1[6]); a7 += b2f(v1[7]);
    }
    a0 += __shfl_xor(a0, 32); a1 += __shfl_xor(a1, 32);
    a2 += __shfl_xor(a2, 32); a3 += __shfl_xor(a3, 32);
    a4 += __shfl_xor(a4, 32); a5 += __shfl_xor(a5, 32);
    a6 += __shfl_xor(a6, 32); a7 += __shfl_xor(a7, 32);
    a0 += __shfl_xor(a0, 16); a1 += __shfl_xor(a1, 16);
    a2 += __shfl_xor(a2, 16); a3 += __shfl_xor(a3, 16);
    a4 += __shfl_xor(a4, 16); a5 += __shfl_xor(a5, 16);
    a6 += __shfl_xor(a6, 16); a7 += __shfl_xor(a7, 16);

    if (slot == 0) {
        float o0 = dd * (a0 + b2f(vs[0])) + bb0.x;
        float o1 = dd * (a1 + b2f(vs[1])) + bb0.y;
        float o2 = dd * (a2 + b2f(vs[2])) + bb0.z;
        float o3 = dd * (a3 + b2f(vs[3])) + bb0.w;
        float o4 = dd * (a4 + b2f(vs[4])) + bb1.x;
        float o5 = dd * (a5 + b2f(vs[5])) + bb1.y;
        float o6 = dd * (a6 + b2f(vs[6])) + bb1.z;
        float o7 = dd * (a7 + b2f(vs[7])) + bb1.w;
        if (OBF) {
            ushort_t tmp[8] __attribute__((aligned(16)));
            tmp[0] = f2b(o0); tmp[1] = f2b(o1); tmp[2] = f2b(o2); tmp[3] = f2b(o3);
            tmp[4] = f2b(o4); tmp[5] = f2b(o5); tmp[6] = f2b(o6); tmp[7] = f2b(o7);
            *(us8v*)((ushort_t*)outp + ((size_t)d << 7) + (j << 3)) = *(const us8v*)tmp;
        } else {
            float4 q0 = { o0, o1, o2, o3 };
            float4 q1 = { o4, o5, o6, o7 };
            float4* po = (float4*)((float*)outp + ((size_t)d << 7) + (j << 3));
            po[0] = q0; po[1] = q1;
        }
    }
}

// ---- launch -------------------------------------------------------------

extern "C" void kernel_launch(void* const* d_in, const int* in_sizes, int n_in,
                              void* d_out, int out_size, void* d_ws, size_t ws_size,
                              hipStream_t stream) {
    const float* x  = (const float*)d_in[0];   // [N,128] f32
    const int*   ei = (const int*)d_in[1];     // [2,E] int32/int64 (detected)
    const float* W1 = (const float*)d_in[2];   // [128,128] f32
    const float* b1 = (const float*)d_in[3];   // [128] f32
    const float* W2 = (const float*)d_in[4];
    const float* b2 = (const float*)d_in[5];
    float* out = (float*)d_out;                // [N,128] f32

    const int N = in_sizes[0] / 128;
    const int E = in_sizes[1] / 2;

    int BSH = 9;
    int NB = (N + (1 << BSH) - 1) >> BSH;
    while (NB > 256) { BSH++; NB = (N + (1 << BSH) - 1) >> BSH; }

    char* ws = (char*)d_ws;
    size_t o = 0;
    auto take = [&](size_t bytes) { size_t r = o; o = (o + bytes + 255) & ~(size_t)255; return r; };
    size_t o_bhist  = take(256 * 4);
    size_t o_cursor = take(4);
    size_t zero_end = o;                  // memset [0, zero_end): bhist + cursor
    size_t o_bkbase = take(256 * 4);
    size_t o_bkcur  = take(256 * 4);
    size_t o_cnt    = take((size_t)N * 4);
    size_t o_pos    = take((size_t)N * 4);
    size_t o_dinv   = take((size_t)N * 4);
    size_t o_srcs   = take(((size_t)E + 7 * (size_t)N + 64) * 4);  // lists padded to 8
    size_t o_WT     = take(2 * 128 * 128 * 2);
    size_t big_sz   = (size_t)E * 8 > (size_t)(N + 1) * 256 ? (size_t)E * 8
                                                            : (size_t)(N + 1) * 256;
    size_t o_big    = take(big_sz);
    (void)ws_size;

    int*      bhist  = (int*)(ws + o_bhist);
    int*      cursor = (int*)(ws + o_cursor);
    int*      bkbase = (int*)(ws + o_bkbase);
    int*      bkcur  = (int*)(ws + o_bkcur);
    int*      cnt    = (int*)(ws + o_cnt);
    int*      pos    = (int*)(ws + o_pos);
    float*    dinv   = (float*)(ws + o_dinv);
    int*      srcs   = (int*)(ws + o_srcs);
    ushort_t* WT     = (ushort_t*)(ws + o_WT);
    int*      bs     = (int*)(ws + o_big);           // CSR-build phase only
    int*      bd     = (int*)(ws + o_big) + E;
    ushort_t* xt     = (ushort_t*)(ws + o_big);      // GEMM phase (after fill)
    ushort_t* hbf    = (ushort_t*)d_out;             // layer-1 bf16 staged in d_out

    hipMemsetAsync(d_ws, 0, zero_end, stream);

    int nch = (E + 4095) / 4096;
    int gN  = (N + 255) / 256;
    int gG  = (N + 63) / 64;
    int gA  = (N + 3) / 4;
    unsigned Nu = (unsigned)N;
    int Ni = N;

    // fused CSR build (cooperative); needs blocks for edge chunks + 3 transpose blocks
    int gridc = nch + 3;
    if (gN > gridc) gridc = gN;
    if (NB > gridc) gridc = NB;

    void* args[] = { (void*)&ei, (void*)&E, (void*)&Nu, (void*)&Ni, (void*)&NB,
                     (void*)&BSH, (void*)&nch, (void*)&gN,
                     (void*)&bhist, (void*)&bkbase, (void*)&bkcur, (void*)&cnt,
                     (void*)&pos, (void*)&dinv, (void*)&cursor, (void*)&srcs,
                     (void*)&bs, (void*)&bd, (void*)&W1, (void*)&W2,
                     (void*)&WT, (void*)&xt };
    hipError_t rc = hipLaunchCooperativeKernel((const void*)k_csr, dim3(gridc),
                                               dim3(256), args, 0, stream);
    if (rc != hipSuccess) {
        // fallback: proven separate-kernel pipeline
        k_hist<<<nch, 256, 0, stream>>>(ei, E, Nu, bhist, BSH, NB);
        k_scanb<<<1, 256, 0, stream>>>(bhist, NB, bkbase, bkcur);
        k_bucket<<<nch, 256, 0, stream>>>(ei, E, Nu, bkcur, bs, bd, BSH, NB);
        k_count2<<<NB, 256, 0, stream>>>(bd, bkbase, bkcur, N, BSH, cnt);
        k_assign<<<gN, 256, 0, stream>>>(cnt, N, pos, dinv, cursor, srcs, N);
        k_fill2<<<NB, 256, 0, stream>>>(bs, bd, bkbase, bkcur, pos, N, BSH, srcs);
        k_transpose<<<3, 256, 0, stream>>>(W1, W2, WT, xt, N);
    }

    // layer 1: xt = bf16(dinv * (x @ W1)); hbf = bf16(agg(xt) + b1)
    k_gemm<false><<<gG, 256, 0, stream>>>(x, WT, xt, dinv, N);
    k_agg<true><<<gA, 256, 0, stream>>>(xt, b1, hbf, pos, cnt, dinv, srcs, N);
    // layer 2: xt = bf16(dinv * (hbf @ W2)); out = agg(xt) + b2 (f32)
    k_gemm<true><<<gG, 256, 0, stream>>>(hbf, WT + 16384, xt, dinv, N);
    k_agg<false><<<gA, 256, 0, stream>>>(xt, b2, out, pos, cnt, dinv, srcs, N);
}

// Round 7
// 330.689 us; speedup vs baseline: 1.7282x; 1.7282x over previous
//
#include <hip/hip_runtime.h>

typedef unsigned short ushort_t;
typedef __attribute__((ext_vector_type(8))) short short8;
typedef __attribute__((ext_vector_type(8))) unsigned short us8v;
typedef __attribute__((ext_vector_type(4))) float f32x4;

__device__ __forceinline__ float b2f(unsigned short u) {
    union { unsigned int i; float f; } v; v.i = ((unsigned int)u) << 16; return v.f;
}
__device__ __forceinline__ unsigned short f2b(float f) {
    union { float f; unsigned int i; } v; v.f = f;
    unsigned int r = (v.i + 0x7FFF + ((v.i >> 16) & 1)) >> 16;
    return (unsigned short)r;
}

// int64 path: low words carry the value (nonneg < 2^31); 8B coalesced loads
__device__ __forceinline__ void load_edge(const int* __restrict__ ei, int e, int E,
                                          int is64, int& s, int& d) {
    if (is64) {
        const long long* el = (const long long*)ei;
        s = (int)el[e]; d = (int)el[E + e];
    } else {
        s = ei[e]; d = ei[E + e];
    }
}

// detection: odd int32 words of first 512 entries all zero => int64
__device__ __forceinline__ int detect64(const int* __restrict__ ei, int t) {
    int z = 0;
    for (int i = t; i < 512; i += 256) z |= ei[2 * i + 1];
    return (__syncthreads_or(z) == 0);
}

// ---- bucket histogram (blocks < nch) + W transpose (2 extra blocks) -----
__global__ __launch_bounds__(256) void k_histT(const int* __restrict__ ei, int E,
                                               unsigned N, int* __restrict__ bhist,
                                               int BSH, int NB, int nch,
                                               const float* __restrict__ W1,
                                               const float* __restrict__ W2,
                                               ushort_t* __restrict__ WT) {
    __shared__ int lh[256];
    int t = threadIdx.x;
    int b = blockIdx.x;
    if (b >= nch) {
        // W transpose + cast: WT[n][k] = W[k][n]
        const float* src = (b == nch) ? W1 : W2;
        ushort_t* dst = WT + (b - nch) * 16384;
        for (int i = t; i < 16384; i += 256) {
            int n = i >> 7, k = i & 127;
            dst[i] = f2b(src[k * 128 + n]);
        }
        return;
    }
    for (int q = t; q < NB; q += 256) lh[q] = 0;
    int is64 = detect64(ei, t);   // includes __syncthreads
    int e0 = b * 4096;
    #pragma unroll
    for (int i = 0; i < 16; ++i) {
        int e = e0 + i * 256 + t;
        if (e < E) {
            int s, d; load_edge(ei, e, E, is64, s, d);
            if ((unsigned)s < N && (unsigned)d < N) atomicAdd(&lh[d >> BSH], 1);
        }
    }
    __syncthreads();
    for (int q = t; q < NB; q += 256) { int v = lh[q]; if (v) atomicAdd(&bhist[q], v); }
}

// ---- exclusive scan of bucket hist (NB <= 256), one block ---------------
__global__ void k_scanb(const int* __restrict__ bhist, int NB,
                        int* __restrict__ bkbase, int* __restrict__ bkcur) {
    __shared__ int sd[256];
    int t = threadIdx.x;
    int v0 = (t < NB) ? bhist[t] : 0;
    sd[t] = v0;
    for (int o = 1; o < 256; o <<= 1) {
        __syncthreads();
        int v = (t >= o) ? sd[t - o] : 0;
        __syncthreads();
        sd[t] += v;
    }
    __syncthreads();
    if (t < NB) { int ex = sd[t] - v0; bkbase[t] = ex; bkcur[t] = ex; }
}

// ---- bucket scatter: edges -> (bs, bd) grouped by destination bucket ----
__global__ __launch_bounds__(256) void k_bucket(const int* __restrict__ ei, int E, unsigned N,
                                                int* __restrict__ bkcur,
                                                int* __restrict__ bs, int* __restrict__ bd,
                                                int BSH, int NB) {
    __shared__ int lss[4096];
    __shared__ int ldd[4096];
    __shared__ int lhist[256];
    __shared__ int lcur[256];
    int t = threadIdx.x;
    int e0 = blockIdx.x * 4096;
    for (int b = t; b < NB; b += 256) lhist[b] = 0;
    int is64 = detect64(ei, t);
    #pragma unroll
    for (int i = 0; i < 16; ++i) {
        int idx = i * 256 + t, e = e0 + idx;
        int s = -1, d = -1;
        if (e < E) {
            load_edge(ei, e, E, is64, s, d);
            if (!((unsigned)s < N && (unsigned)d < N)) d = -1;
        }
        lss[idx] = s; ldd[idx] = d;
        if (d >= 0) atomicAdd(&lhist[d >> BSH], 1);
    }
    __syncthreads();
    for (int b = t; b < NB; b += 256) {
        int v = lhist[b];
        lcur[b] = v ? atomicAdd(&bkcur[b], v) : 0;
    }
    __syncthreads();
    #pragma unroll
    for (int i = 0; i < 16; ++i) {
        int idx = i * 256 + t;
        int d = ldd[idx];
        if (d >= 0) {
            int p = atomicAdd(&lcur[d >> BSH], 1);
            bs[p] = lss[idx]; bd[p] = d;
        }
    }
}

// ---- fused count + padded-scan/assign + fill, all bucket-local ----------
// Bucket b's srcs segment starts at bkbase[b] + b*PADMAX (PADMAX = 7<<BSH).
// No global cursor, no cross-block dependency.
__global__ __launch_bounds__(256) void k_caf(const int* __restrict__ bs,
                                             const int* __restrict__ bd,
                                             const int* __restrict__ bkbase,
                                             const int* __restrict__ bkcur,
                                             int N, int BSH,
                                             int* __restrict__ pos,
                                             int* __restrict__ cnt,
                                             float* __restrict__ dinv,
                                             int* __restrict__ srcs) {
    __shared__ int lc[512];   // counts, then fill cursors
    __shared__ int sc[512];   // padded-count inclusive scan
    int b = blockIdx.x, t = threadIdx.x;
    int nbase = b << BSH;
    int nn = min(1 << BSH, N - nbase);
    int segbase = bkbase[b] + b * (7 << BSH);

    lc[t] = 0; lc[t + 256] = 0;
    __syncthreads();
    int s0 = bkbase[b], s1 = bkcur[b];
    for (int i = s0 + t; i < s1; i += 256) atomicAdd(&lc[bd[i] - nbase], 1);
    __syncthreads();

    int c0 = (t < nn) ? lc[t] : 0;
    int c1 = (t + 256 < nn) ? lc[t + 256] : 0;
    int p0 = (c0 + 7) & ~7;                // pad each list to multiple of 8
    int p1 = (c1 + 7) & ~7;
    sc[t] = p0; sc[t + 256] = p1;
    __syncthreads();
    for (int o = 1; o < 512; o <<= 1) {
        int v0 = (t >= o) ? sc[t - o] : 0;
        int v1 = (t + 256 >= o) ? sc[t + 256 - o] : 0;
        __syncthreads();
        sc[t] += v0; sc[t + 256] += v1;
        __syncthreads();
    }
    // write pos/cnt/dinv + pad entries; seed fill cursors
    if (t < nn) {
        int st = segbase + sc[t] - p0;
        pos[nbase + t] = st;
        cnt[nbase + t] = p0;
        dinv[nbase + t] = rsqrtf((float)c0 + 1.0f);
        for (int q = c0; q < p0; ++q) srcs[st + q] = N;   // pads -> zero row
        lc[t] = st;
    }
    if (t + 256 < nn) {
        int st = segbase + sc[t + 256] - p1;
        pos[nbase + t + 256] = st;
        cnt[nbase + t + 256] = p1;
        dinv[nbase + t + 256] = rsqrtf((float)c1 + 1.0f);
        for (int q = c1; q < p1; ++q) srcs[st + q] = N;
        lc[t + 256] = st;
    }
    __syncthreads();
    // fill
    for (int i = s0 + t; i < s1; i += 256) {
        int d = bd[i];
        int p = atomicAdd(&lc[d - nbase], 1);
        srcs[p] = bs[i];
    }
}

// ---- GEMM: C[M,128] = dinv[m] * (A[M,128] @ W[128,128]); C bf16 ---------
// A is f32 (layer 1) or bf16 (layer 2). ZROW: block 0 zeroes C row M
// (the pad-gather zero row) — ordered after bs/bd's last use via launch order.
template <bool ABF, bool ZROW>
__global__ __launch_bounds__(256) void k_gemm(const void* __restrict__ Ap,
                                              const ushort_t* __restrict__ WT,
                                              ushort_t* __restrict__ C,
                                              const float* __restrict__ dinv, int M) {
    __shared__ __align__(16) ushort_t sA[64 * 136];
    __shared__ __align__(16) ushort_t sW[128 * 136];
    int t = threadIdx.x;
    int row0 = blockIdx.x * 64;

    if (ZROW && blockIdx.x == 0 && t < 128) C[((size_t)M << 7) + t] = 0;

    #pragma unroll
    for (int it = 0; it < 8; ++it) {
        int flat = (it * 256 + t) * 8;
        int n = flat >> 7, k = flat & 127;
        uint4 v = *(const uint4*)(WT + flat);
        *(uint4*)(&sW[n * 136 + k]) = v;
    }
    #pragma unroll
    for (int it = 0; it < 4; ++it) {
        int flat = (it * 256 + t) * 8;
        int r = flat >> 7, cc = flat & 127;
        int row = row0 + r; if (row > M - 1) row = M - 1;
        if (ABF) {
            const ushort_t* A = (const ushort_t*)Ap;
            us8v v = *(const us8v*)(A + ((size_t)row << 7) + cc);
            *(us8v*)(&sA[r * 136 + cc]) = v;
        } else {
            const float* A = (const float*)Ap;
            const float* p = A + (size_t)row * 128 + cc;
            float4 f0 = *(const float4*)p;
            float4 f1 = *(const float4*)(p + 4);
            ushort_t tmp[8] __attribute__((aligned(16)));
            tmp[0] = f2b(f0.x); tmp[1] = f2b(f0.y); tmp[2] = f2b(f0.z); tmp[3] = f2b(f0.w);
            tmp[4] = f2b(f1.x); tmp[5] = f2b(f1.y); tmp[6] = f2b(f1.z); tmp[7] = f2b(f1.w);
            *(uint4*)(&sA[r * 136 + cc]) = *(const uint4*)tmp;
        }
    }
    __syncthreads();

    int w = t >> 6, lane = t & 63;
    int m = lane & 15, quad = lane >> 4;

    f32x4 acc[8] = {};
    #pragma unroll
    for (int k0 = 0; k0 < 128; k0 += 32) {
        short8 af = *(const short8*)(&sA[(w * 16 + m) * 136 + k0 + quad * 8]);
        #pragma unroll
        for (int tt = 0; tt < 8; ++tt) {
            short8 bf = *(const short8*)(&sW[(tt * 16 + m) * 136 + k0 + quad * 8]);
            acc[tt] = __builtin_amdgcn_mfma_f32_16x16x32_bf16(af, bf, acc[tt], 0, 0, 0);
        }
    }
    #pragma unroll
    for (int r = 0; r < 4; ++r) {
        int row = row0 + w * 16 + quad * 4 + r;
        if (row < M) {
            float dd = dinv[row];
            #pragma unroll
            for (int tt = 0; tt < 8; ++tt)
                C[(size_t)row * 128 + tt * 16 + m] = f2b(dd * acc[tt][r]);
        }
    }
}

// ---- Aggregation over pre-scaled xt: out[d] = dinv[d]*(sum + xt[d]) + b -
// Wave per destination; 4 edge-slots x 16 lanes x us8 (8 features, 16B).
// Lists padded to multiples of 8 with the zero row. 2-deep pipeline.
// OBF: write output as bf16 (layer 1 handoff) instead of f32.
template <bool OBF>
__global__ __launch_bounds__(256) void k_agg(const ushort_t* __restrict__ xt,
                                             const float* __restrict__ bias,
                                             void* __restrict__ outp,
                                             const int* __restrict__ pos,
                                             const int* __restrict__ cnts,
                                             const float* __restrict__ dinv,
                                             const int* __restrict__ srcs, int N) {
    int lane = threadIdx.x & 63;
    int slot = lane >> 4, j = lane & 15;
    int d = (blockIdx.x << 2) + (threadIdx.x >> 6);
    if (d >= N) return;
    int cn = cnts[d];                       // padded (multiple of 8)
    int start = pos[d];
    float dd = dinv[d];
    us8v vs = *(const us8v*)(xt + ((size_t)d << 7) + (j << 3));
    float4 bb0 = *(const float4*)(bias + (j << 3));
    float4 bb1 = *(const float4*)(bias + (j << 3) + 4);

    float a0 = 0.f, a1 = 0.f, a2 = 0.f, a3 = 0.f;
    float a4 = 0.f, a5 = 0.f, a6 = 0.f, a7 = 0.f;

    for (int base = 0; base < cn; base += 64) {
        int n = cn - base; if (n > 64) n = 64;   // multiple of 8, >= 8
        int sv = 0;
        if (lane < n) sv = srcs[start + base + lane];
        int s0 = __shfl(sv, slot);
        int s1 = __shfl(sv, 4 + slot);
        us8v v0 = *(const us8v*)(xt + ((size_t)s0 << 7) + (j << 3));
        us8v v1 = *(const us8v*)(xt + ((size_t)s1 << 7) + (j << 3));
        for (int c = 8; c < n; c += 8) {
            int t0 = __shfl(sv, c + slot);
            int t1 = __shfl(sv, c + 4 + slot);
            us8v w0 = *(const us8v*)(xt + ((size_t)t0 << 7) + (j << 3));
            us8v w1 = *(const us8v*)(xt + ((size_t)t1 << 7) + (j << 3));
            a0 += b2f(v0[0]); a1 += b2f(v0[1]); a2 += b2f(v0[2]); a3 += b2f(v0[3]);
            a4 += b2f(v0[4]); a5 += b2f(v0[5]); a6 += b2f(v0[6]); a7 += b2f(v0[7]);
            a0 += b2f(v1[0]); a1 += b2f(v1[1]); a2 += b2f(v1[2]); a3 += b2f(v1[3]);
            a4 += b2f(v1[4]); a5 += b2f(v1[5]); a6 += b2f(v1[6]); a7 += b2f(v1[7]);
            v0 = w0; v1 = w1;
        }
        a0 += b2f(v0[0]); a1 += b2f(v0[1]); a2 += b2f(v0[2]); a3 += b2f(v0[3]);
        a4 += b2f(v0[4]); a5 += b2f(v0[5]); a6 += b2f(v0[6]); a7 += b2f(v0[7]);
        a0 += b2f(v1[0]); a1 += b2f(v1[1]); a2 += b2f(v1[2]); a3 += b2f(v1[3]);
        a4 += b2f(v1[4]); a5 += b2f(v1[5]); a6 += b2f(v1[6]); a7 += b2f(v1[7]);
    }
    a0 += __shfl_xor(a0, 32); a1 += __shfl_xor(a1, 32);
    a2 += __shfl_xor(a2, 32); a3 += __shfl_xor(a3, 32);
    a4 += __shfl_xor(a4, 32); a5 += __shfl_xor(a5, 32);
    a6 += __shfl_xor(a6, 32); a7 += __shfl_xor(a7, 32);
    a0 += __shfl_xor(a0, 16); a1 += __shfl_xor(a1, 16);
    a2 += __shfl_xor(a2, 16); a3 += __shfl_xor(a3, 16);
    a4 += __shfl_xor(a4, 16); a5 += __shfl_xor(a5, 16);
    a6 += __shfl_xor(a6, 16); a7 += __shfl_xor(a7, 16);

    if (slot == 0) {
        float o0 = dd * (a0 + b2f(vs[0])) + bb0.x;
        float o1 = dd * (a1 + b2f(vs[1])) + bb0.y;
        float o2 = dd * (a2 + b2f(vs[2])) + bb0.z;
        float o3 = dd * (a3 + b2f(vs[3])) + bb0.w;
        float o4 = dd * (a4 + b2f(vs[4])) + bb1.x;
        float o5 = dd * (a5 + b2f(vs[5])) + bb1.y;
        float o6 = dd * (a6 + b2f(vs[6])) + bb1.z;
        float o7 = dd * (a7 + b2f(vs[7])) + bb1.w;
        if (OBF) {
            ushort_t tmp[8] __attribute__((aligned(16)));
            tmp[0] = f2b(o0); tmp[1] = f2b(o1); tmp[2] = f2b(o2); tmp[3] = f2b(o3);
            tmp[4] = f2b(o4); tmp[5] = f2b(o5); tmp[6] = f2b(o6); tmp[7] = f2b(o7);
            *(us8v*)((ushort_t*)outp + ((size_t)d << 7) + (j << 3)) = *(const us8v*)tmp;
        } else {
            float4 q0 = { o0, o1, o2, o3 };
            float4 q1 = { o4, o5, o6, o7 };
            float4* po = (float4*)((float*)outp + ((size_t)d << 7) + (j << 3));
            po[0] = q0; po[1] = q1;
        }
    }
}

// ---- launch -------------------------------------------------------------

extern "C" void kernel_launch(void* const* d_in, const int* in_sizes, int n_in,
                              void* d_out, int out_size, void* d_ws, size_t ws_size,
                              hipStream_t stream) {
    const float* x  = (const float*)d_in[0];   // [N,128] f32
    const int*   ei = (const int*)d_in[1];     // [2,E] int32/int64 (detected)
    const float* W1 = (const float*)d_in[2];   // [128,128] f32
    const float* b1 = (const float*)d_in[3];   // [128] f32
    const float* W2 = (const float*)d_in[4];
    const float* b2 = (const float*)d_in[5];
    float* out = (float*)d_out;                // [N,128] f32

    const int N = in_sizes[0] / 128;
    const int E = in_sizes[1] / 2;

    // bucket size 2^BSH nodes, NB <= 256 buckets (N=100000 -> BSH=9, NB=196)
    int BSH = 9;
    int NB = (N + (1 << BSH) - 1) >> BSH;
    while (NB > 256) { BSH++; NB = (N + (1 << BSH) - 1) >> BSH; }

    // workspace (256B-aligned); bs/bd overlap xt (disjoint lifetimes)
    char* ws = (char*)d_ws;
    size_t o = 0;
    auto take = [&](size_t bytes) { size_t r = o; o = (o + bytes + 255) & ~(size_t)255; return r; };
    size_t o_bhist  = take(256 * 4);
    size_t zero_end = o;                  // memset [0, zero_end): bhist
    size_t o_bkbase = take(256 * 4);
    size_t o_bkcur  = take(256 * 4);
    size_t o_cnt    = take((size_t)N * 4);
    size_t o_pos    = take((size_t)N * 4);
    size_t o_dinv   = take((size_t)N * 4);
    // per-bucket padded segments: E + NB * (7<<BSH) entries + slack
    size_t o_srcs   = take(((size_t)E + (size_t)NB * (7 << BSH) + 64) * 4);
    size_t o_WT     = take(2 * 128 * 128 * 2);
    size_t big_sz   = (size_t)E * 8 > (size_t)(N + 1) * 256 ? (size_t)E * 8
                                                            : (size_t)(N + 1) * 256;
    size_t o_big    = take(big_sz);
    (void)ws_size;

    int*      bhist  = (int*)(ws + o_bhist);
    int*      bkbase = (int*)(ws + o_bkbase);
    int*      bkcur  = (int*)(ws + o_bkcur);
    int*      cnt    = (int*)(ws + o_cnt);
    int*      pos    = (int*)(ws + o_pos);
    float*    dinv   = (float*)(ws + o_dinv);
    int*      srcs   = (int*)(ws + o_srcs);
    ushort_t* WT     = (ushort_t*)(ws + o_WT);
    int*      bs     = (int*)(ws + o_big);           // CSR-build phase only
    int*      bd     = (int*)(ws + o_big) + E;
    ushort_t* xt     = (ushort_t*)(ws + o_big);      // GEMM phase (after k_caf)
    ushort_t* hbf    = (ushort_t*)d_out;             // layer-1 bf16 staged in d_out

    hipMemsetAsync(d_ws, 0, zero_end, stream);

    int nch = (E + 4095) / 4096;
    int gG  = (N + 63) / 64;
    int gA  = (N + 3) / 4;
    unsigned Nu = (unsigned)N;

    k_histT<<<nch + 2, 256, 0, stream>>>(ei, E, Nu, bhist, BSH, NB, nch, W1, W2, WT);
    k_scanb<<<1, 256, 0, stream>>>(bhist, NB, bkbase, bkcur);
    k_bucket<<<nch, 256, 0, stream>>>(ei, E, Nu, bkcur, bs, bd, BSH, NB);
    k_caf<<<NB, 256, 0, stream>>>(bs, bd, bkbase, bkcur, N, BSH, pos, cnt, dinv, srcs);

    // layer 1: xt = bf16(dinv * (x @ W1)) (+ zero row); hbf = bf16(agg + b1)
    k_gemm<false, true><<<gG, 256, 0, stream>>>(x, WT, xt, dinv, N);
    k_agg<true><<<gA, 256, 0, stream>>>(xt, b1, hbf, pos, cnt, dinv, srcs, N);
    // layer 2: xt = bf16(dinv * (hbf @ W2)); out = agg(xt) + b2 (f32)
    k_gemm<true, false><<<gG, 256, 0, stream>>>(hbf, WT + 16384, xt, dinv, N);
    k_agg<false><<<gA, 256, 0, stream>>>(xt, b2, out, pos, cnt, dinv, srcs, N);
}